// Round 3
// baseline (200.052 us; speedup 1.0000x reference)
//
#include <hip/hip_runtime.h>
#include <stdint.h>

#define NBINS 1000
#define MMB   2048          // minmax grid blocks == number of min/max slots
#define HB    1024          // hist grid blocks
#define NCOPY 16            // interleaved global histogram copies (power of 2)

// W layout (uints):
//   [0 .. 2*MMB)                      per-block {min,max} as raw float bits
//   [HBASE .. HBASE + NCOPY*2*NBINS)  hist copies: copy c = hp[1000] then ht[1000]
//   [CNT]                             done-counter for last-block finalize
#define HBASE (2 * MMB)
#define CNT   (HBASE + NCOPY * 2 * NBINS)

__device__ __forceinline__ void mm4(float4 v, float& mn, float& mx) {
    mn = fminf(mn, fminf(fminf(v.x, v.y), fminf(v.z, v.w)));
    mx = fmaxf(mx, fmaxf(fmaxf(v.x, v.y), fmaxf(v.z, v.w)));
}

__global__ void __launch_bounds__(256) minmax_kernel(
        const float* __restrict__ p, const float* __restrict__ t,
        long long n, unsigned* __restrict__ W) {
    // first 64 blocks zero the global hist copies + counter (hist launches after us)
    if (blockIdx.x < 64) {
        const int per = (NCOPY * 2 * NBINS) / 64;  // 500
        int base = HBASE + blockIdx.x * per;
        for (int i = threadIdx.x; i < per; i += 256) W[base + i] = 0u;
        if (blockIdx.x == 0 && threadIdx.x == 0) W[CNT] = 0u;
    }

    long long n4 = n >> 2;
    const float4* p4 = (const float4*)p;
    const float4* t4 = (const float4*)t;
    // contiguous chunk per block: sequential 4KB-row walk, 8 float4 loads in flight
    long long C = (n4 + MMB - 1) / MMB;
    long long s0 = (long long)blockIdx.x * C;
    long long e = s0 + C;
    if (e > n4) e = n4;

    float mn = __builtin_inff();
    float mx = -__builtin_inff();
    long long i = s0 + threadIdx.x;
    for (; i + 768 < e; i += 1024) {
        float4 a0 = p4[i];
        float4 a1 = p4[i + 256];
        float4 a2 = p4[i + 512];
        float4 a3 = p4[i + 768];
        float4 b0 = t4[i];
        float4 b1 = t4[i + 256];
        float4 b2 = t4[i + 512];
        float4 b3 = t4[i + 768];
        mm4(a0, mn, mx); mm4(a1, mn, mx); mm4(a2, mn, mx); mm4(a3, mn, mx);
        mm4(b0, mn, mx); mm4(b1, mn, mx); mm4(b2, mn, mx); mm4(b3, mn, mx);
    }
    for (; i < e; i += 256) {
        mm4(p4[i], mn, mx);
        mm4(t4[i], mn, mx);
    }
    // scalar tail (n % 4) handled by the last block
    if (blockIdx.x == gridDim.x - 1) {
        for (long long j = (n4 << 2) + threadIdx.x; j < n; j += 256) {
            float a = p[j], b = t[j];
            mn = fminf(mn, fminf(a, b));
            mx = fmaxf(mx, fmaxf(a, b));
        }
    }

    __shared__ float smin[256];
    __shared__ float smax[256];
    int tid = threadIdx.x;
    smin[tid] = mn; smax[tid] = mx;
    __syncthreads();
    for (int s = 128; s > 0; s >>= 1) {
        if (tid < s) {
            smin[tid] = fminf(smin[tid], smin[tid + s]);
            smax[tid] = fmaxf(smax[tid], smax[tid + s]);
        }
        __syncthreads();
    }
    if (tid == 0) {
        W[2 * blockIdx.x]     = __float_as_uint(smin[0]);
        W[2 * blockIdx.x + 1] = __float_as_uint(smax[0]);
    }
}

// count of v <= x_j  ==  sum_{k<=j} hist[k]  with  hist bin k = ceil((v-lo)/dx)
__device__ __forceinline__ int binof(float v, float lo, float inv_dx) {
    float u = (v - lo) * inv_dx;
    int k = (int)ceilf(u);
    return min(max(k, 0), NBINS - 1);
}

__device__ __forceinline__ void hist4v(float4 v, unsigned* h, float lo, float inv_dx) {
    atomicAdd(&h[binof(v.x, lo, inv_dx)], 1u);
    atomicAdd(&h[binof(v.y, lo, inv_dx)], 1u);
    atomicAdd(&h[binof(v.z, lo, inv_dx)], 1u);
    atomicAdd(&h[binof(v.w, lo, inv_dx)], 1u);
}

__global__ void __launch_bounds__(256) hist_kernel(
        const float* __restrict__ p, const float* __restrict__ t,
        long long n, unsigned* __restrict__ W, float* __restrict__ out) {
    __shared__ unsigned hp[NBINS];
    __shared__ unsigned ht[NBINS];
    __shared__ float sred[256];
    __shared__ unsigned done;
    __shared__ unsigned long long su[256];
    __shared__ double rd[256];
    int tid = threadIdx.x;

    // lo/hi from the MMB per-block slots (written by previous kernel)
    float lmn = __builtin_inff(), lmx = -__builtin_inff();
    for (int i = tid; i < MMB; i += 256) {
        lmn = fminf(lmn, __uint_as_float(W[2 * i]));
        lmx = fmaxf(lmx, __uint_as_float(W[2 * i + 1]));
    }
    for (int i = tid; i < NBINS; i += 256) { hp[i] = 0u; ht[i] = 0u; }
    sred[tid] = lmn;
    __syncthreads();
    for (int s = 128; s > 0; s >>= 1) {
        if (tid < s) sred[tid] = fminf(sred[tid], sred[tid + s]);
        __syncthreads();
    }
    float lo = sred[0];
    __syncthreads();
    sred[tid] = lmx;
    __syncthreads();
    for (int s = 128; s > 0; s >>= 1) {
        if (tid < s) sred[tid] = fmaxf(sred[tid], sred[tid + s]);
        __syncthreads();
    }
    float hi = sred[0];
    __syncthreads();

    float inv_dx = (float)(NBINS - 1) / (hi - lo);

    long long n4 = n >> 2;
    const float4* p4 = (const float4*)p;
    const float4* t4 = (const float4*)t;
    long long C = (n4 + HB - 1) / HB;
    long long s0 = (long long)blockIdx.x * C;
    long long e = s0 + C;
    if (e > n4) e = n4;

    long long i = s0 + tid;
    for (; i + 768 < e; i += 1024) {
        float4 a0 = p4[i];
        float4 a1 = p4[i + 256];
        float4 a2 = p4[i + 512];
        float4 a3 = p4[i + 768];
        float4 b0 = t4[i];
        float4 b1 = t4[i + 256];
        float4 b2 = t4[i + 512];
        float4 b3 = t4[i + 768];
        hist4v(a0, hp, lo, inv_dx); hist4v(a1, hp, lo, inv_dx);
        hist4v(a2, hp, lo, inv_dx); hist4v(a3, hp, lo, inv_dx);
        hist4v(b0, ht, lo, inv_dx); hist4v(b1, ht, lo, inv_dx);
        hist4v(b2, ht, lo, inv_dx); hist4v(b3, ht, lo, inv_dx);
    }
    for (; i < e; i += 256) {
        hist4v(p4[i], hp, lo, inv_dx);
        hist4v(t4[i], ht, lo, inv_dx);
    }
    if (blockIdx.x == gridDim.x - 1) {
        for (long long j = (n4 << 2) + tid; j < n; j += 256) {
            atomicAdd(&hp[binof(p[j], lo, inv_dx)], 1u);
            atomicAdd(&ht[binof(t[j], lo, inv_dx)], 1u);
        }
    }
    __syncthreads();

    // flush into one of NCOPY interleaved copies; stagger start to spread bursts
    unsigned* cpb = W + HBASE + (blockIdx.x & (NCOPY - 1)) * (2 * NBINS);
    int shift = (int)((blockIdx.x * 61u) % (unsigned)NBINS);
    for (int k = tid; k < NBINS; k += 256) {
        int b = k + shift;
        if (b >= NBINS) b -= NBINS;
        unsigned c0 = hp[b];
        unsigned c1 = ht[b];
        if (c0) atomicAdd(&cpb[b], c0);
        if (c1) atomicAdd(&cpb[NBINS + b], c1);
    }

    // ---- last-arriving block finalizes (no spin: deadlock-free) ----
    __syncthreads();   // compiler drains vmcnt here -> all flush atomics performed
    if (tid == 0) {
        __threadfence();
        done = atomicAdd(&W[CNT], 1u);
    }
    __syncthreads();
    if (done != (unsigned)(gridDim.x - 1)) return;
    __threadfence();

    // sum the NCOPY copies: 4 consecutive bins per thread, packed u64 (cp low, ct high)
    int j0 = tid * 4;
    unsigned long long b0 = 0ull, b1 = 0ull, b2 = 0ull, b3 = 0ull;
    if (j0 < NBINS) {
        unsigned cp0 = 0, cp1 = 0, cp2 = 0, cp3 = 0;
        unsigned ct0 = 0, ct1 = 0, ct2 = 0, ct3 = 0;
        for (int c = 0; c < NCOPY; ++c) {
            const unsigned* base = W + HBASE + c * (2 * NBINS);
            // agent-scope atomic loads: values live at the coherent point
            cp0 += __hip_atomic_load(&base[j0 + 0], __ATOMIC_RELAXED, __HIP_MEMORY_SCOPE_AGENT);
            cp1 += __hip_atomic_load(&base[j0 + 1], __ATOMIC_RELAXED, __HIP_MEMORY_SCOPE_AGENT);
            cp2 += __hip_atomic_load(&base[j0 + 2], __ATOMIC_RELAXED, __HIP_MEMORY_SCOPE_AGENT);
            cp3 += __hip_atomic_load(&base[j0 + 3], __ATOMIC_RELAXED, __HIP_MEMORY_SCOPE_AGENT);
            ct0 += __hip_atomic_load(&base[NBINS + j0 + 0], __ATOMIC_RELAXED, __HIP_MEMORY_SCOPE_AGENT);
            ct1 += __hip_atomic_load(&base[NBINS + j0 + 1], __ATOMIC_RELAXED, __HIP_MEMORY_SCOPE_AGENT);
            ct2 += __hip_atomic_load(&base[NBINS + j0 + 2], __ATOMIC_RELAXED, __HIP_MEMORY_SCOPE_AGENT);
            ct3 += __hip_atomic_load(&base[NBINS + j0 + 3], __ATOMIC_RELAXED, __HIP_MEMORY_SCOPE_AGENT);
        }
        b0 = (unsigned long long)cp0 | ((unsigned long long)ct0 << 32);
        b1 = (unsigned long long)cp1 | ((unsigned long long)ct1 << 32);
        b2 = (unsigned long long)cp2 | ((unsigned long long)ct2 << 32);
        b3 = (unsigned long long)cp3 | ((unsigned long long)ct3 << 32);
    }
    // thread-local inclusive prefix (counts < 2^25: halves never carry-cross)
    unsigned long long l0 = b0, l1 = l0 + b1, l2 = l1 + b2, l3 = l2 + b3;
    unsigned long long T = l3;
    su[tid] = T;
    __syncthreads();
    for (int off = 1; off < 256; off <<= 1) {
        unsigned long long v = (tid >= off) ? su[tid - off] : 0ull;
        __syncthreads();
        su[tid] += v;
        __syncthreads();
    }
    unsigned long long E = su[tid] - T;  // exclusive prefix of this thread's 4 bins

    double ys = 0.0;
    if (j0 < NBINS) {
        float invn = 1.0f / (float)n;
        unsigned long long incl[4] = { E + l0, E + l1, E + l2, E + l3 };
        for (int q = 0; q < 4; ++q) {
            int j = j0 + q;
            unsigned cpv = (unsigned)(incl[q] & 0xFFFFFFFFull);
            unsigned ctv = (unsigned)(incl[q] >> 32);
            float d = (float)cpv * invn - (float)ctv * invn;
            float yy = d * d;
            float w = (j == 0 || j == NBINS - 1) ? 0.5f : 1.0f;
            ys += (double)yy * (double)w;
        }
    }
    rd[tid] = ys;
    __syncthreads();
    for (int s = 128; s > 0; s >>= 1) {
        if (tid < s) rd[tid] += rd[tid + s];
        __syncthreads();
    }
    if (tid == 0) {
        double dx = (double)(hi - lo) / (double)(NBINS - 1);
        out[0] = (float)(rd[0] * dx);
    }
}

extern "C" void kernel_launch(void* const* d_in, const int* in_sizes, int n_in,
                              void* d_out, int out_size, void* d_ws, size_t ws_size,
                              hipStream_t stream) {
    const float* p = (const float*)d_in[0];
    const float* t = (const float*)d_in[1];
    float* out = (float*)d_out;
    long long n = (long long)in_sizes[0];

    unsigned* W = (unsigned*)d_ws;

    minmax_kernel<<<MMB, 256, 0, stream>>>(p, t, n, W);
    hist_kernel<<<HB, 256, 0, stream>>>(p, t, n, W, out);
}